// Round 13
// baseline (193.472 us; speedup 1.0000x reference)
//
#include <hip/hip_runtime.h>
#include <hip/hip_bf16.h>

// AttentionConv2d: B=8, C_IN=256, H=W=32 (HW=1024), DK=DV=256, NH=8, DKH=DVH=32,
// C_OUT=512, 3x3 conv pad=1. fp32 storage in/out; bf16 intermediates + MFMA.
//
// Workspace (bf16 elements, EXACTLY 16 MB):
//   xT    [8 b][1024 l][256 ci]  @ 0          read by fused conv3+qkv
//   attL  [8 b][1024 l][256 ch]  @ 0          alias of xT (attn writes after fused done)
//   qT    [64 head][1024][32]    @ 2,097,152
//   kR    [64 head][1024][32]    @ 4,194,304
//   vW    [64 head][32][1024]    @ 6,291,456
// wo_bf (prepacked bf16 conv3 weights) lives in D_OUT's attention half (ch256+),
// dead from launch until attnout overwrites it. prep -> convqkv -> attn -> attnout.
// R13: attn K-loop double-buffered (1 barrier/chunk) + pS/vtS stride 72->68
// (write conflicts eliminated, read aliasing 8-way -> 4-way).

typedef __hip_bfloat16 bf16;
typedef __attribute__((ext_vector_type(8))) short bf16x8;
typedef __attribute__((ext_vector_type(4))) float f32x4;

__device__ __forceinline__ float bf2f(bf16 v) { return __bfloat162float(v); }
__device__ __forceinline__ float blo(unsigned int v) { return __uint_as_float(v << 16); }
__device__ __forceinline__ float bhi(unsigned int v) { return __uint_as_float(v & 0xffff0000u); }
__device__ __forceinline__ unsigned short f2bfbits(float f) {
  union { bf16 h; unsigned short u; } cv; cv.h = __float2bfloat16(f); return cv.u;
}
// cheap round-to-nearest (ties away): 2 VALU ops; <=1 ulp vs RNE.
__device__ __forceinline__ short f2bfr(float f) {
  return (short)((__float_as_uint(f) + 0x8000u) >> 16);
}

// ---------------------------------------------------------------------------
// K0: prep — xT transpose to bf16 + w_out bf16 chunk-blocked into wob0/wob1.
// blocks 0..2047: xT; 2048..2083: w_out. grid 2084.
// ---------------------------------------------------------------------------
__global__ __launch_bounds__(256) void prep_kernel(
    const float* __restrict__ x, const float* __restrict__ wout,
    bf16* __restrict__ xT, bf16* __restrict__ wob0, bf16* __restrict__ wob1)
{
  int bid = blockIdx.x, tid = threadIdx.x;
  if (bid < 2048) {
    __shared__ float t[32 * 33];
    int b = bid >> 8, rem = bid & 255;
    int ci0 = (rem >> 5) * 32, l0 = (rem & 31) * 32;
    {
      int ciL = tid >> 3, lL4 = (tid & 7) * 4;
      float4 v = *(const float4*)(x + (size_t)(b * 256 + ci0 + ciL) * 1024 + l0 + lL4);
      t[ciL * 33 + lL4 + 0] = v.x; t[ciL * 33 + lL4 + 1] = v.y;
      t[ciL * 33 + lL4 + 2] = v.z; t[ciL * 33 + lL4 + 3] = v.w;
    }
    __syncthreads();
    {
      int lL = tid >> 3, cS = (tid & 7) * 4;
      unsigned int p0 = (unsigned int)f2bfbits(t[(cS + 0) * 33 + lL]) |
                        ((unsigned int)f2bfbits(t[(cS + 1) * 33 + lL]) << 16);
      unsigned int p1 = (unsigned int)f2bfbits(t[(cS + 2) * 33 + lL]) |
                        ((unsigned int)f2bfbits(t[(cS + 3) * 33 + lL]) << 16);
      uint2 u2; u2.x = p0; u2.y = p1;
      *(uint2*)(xT + ((size_t)(b * 1024) + l0 + lL) * 256 + ci0 + cS) = u2;
    }
  } else {
    int t0 = (bid - 2048) * 256 + tid;       // 0..9215
#pragma unroll
    for (int s = 0; s < 8; ++s) {
      int u = s * 9216 + t0;                 // dst uint4 index 0..73727
      int chunkblk = u / 2304;
      int within = u - chunkblk * 2304;
      int co63 = within / 36;
      int r = within - co63 * 36;            // kidx*4 + cig
      int kidx = r >> 2, cig = r & 3;
      int co = (chunkblk >> 3) * 64 + co63;
      int ci = (chunkblk & 7) * 32 + cig * 8;
      union { unsigned short h[8]; uint4 u4; } pk;
#pragma unroll
      for (int j = 0; j < 8; ++j)
        pk.h[j] = f2bfbits(wout[(size_t)(co * 256 + ci + j) * 9 + kidx]);
      bf16* dst = (chunkblk < 28) ? (wob0 + (size_t)chunkblk * 18432)
                                  : (wob1 + (size_t)(chunkblk - 28) * 18432);
      *(uint4*)(dst + (size_t)within * 8) = pk.u4;
    }
  }
}

// ---------------------------------------------------------------------------
// K1 (fused): blocks 0..255 = conv3 (3x3, MFMA shift-GEMM, prepacked weights);
// 256..1023 = qkv GEMM. Both only read xT -> co-resident, mutual latency hiding.
// ---------------------------------------------------------------------------
__global__ __launch_bounds__(256) void convqkv_kernel(
    const bf16* __restrict__ xT,
    const bf16* __restrict__ wob0, const bf16* __restrict__ wob1,
    const float* __restrict__ b_out, float* __restrict__ out,
    const float* __restrict__ wq, const float* __restrict__ b_qkv,
    bf16* __restrict__ qT, bf16* __restrict__ kR, bf16* __restrict__ vW)
{
  __shared__ __align__(16) short smem[27104];
  int tid = threadIdx.x, lane = tid & 63, wave = tid >> 6;
  int m16 = lane & 15, quad = lane >> 4;

  if (blockIdx.x < 256) {
    short* wS = smem;            // [64 co][296]
    short* xS = smem + 18944;    // [6 rows][34 cols][40]
    int bid = blockIdx.x;
    int rc = bid & 7, cotile = (bid >> 3) & 3, b = bid >> 5;
    int y0 = rc * 4;

    f32x4 acc[8];
#pragma unroll
    for (int t = 0; t < 8; ++t) acc[t] = (f32x4){0.f, 0.f, 0.f, 0.f};

    for (int ck = 0; ck < 8; ++ck) {
      __syncthreads();
      int cb = cotile * 8 + ck;
      const bf16* wbase = (cb < 28) ? (wob0 + (size_t)cb * 18432)
                                    : (wob1 + (size_t)(cb - 28) * 18432);
#pragma unroll
      for (int r = 0; r < 9; ++r) {
        int u = r * 256 + tid;
        *(uint4*)(wS + (u / 36) * 296 + (u % 36) * 8) = *(const uint4*)(wbase + (size_t)u * 8);
      }
#pragma unroll
      for (int r = 0; r < 3; ++r) {
        int u = r * 256 + tid;
        int pos = u >> 2, seg = u & 3;
        int row = pos >> 5, col = pos & 31;
        int gy = y0 - 1 + row;
        uint4 val = make_uint4(0u, 0u, 0u, 0u);
        if (gy >= 0 && gy < 32)
          val = *(const uint4*)(xT + ((size_t)(b * 1024) + gy * 32 + col) * 256 + ck * 32 + seg * 8);
        *(uint4*)(xS + (row * 34 + col + 1) * 40 + seg * 8) = val;
      }
      if (tid < 48) {
        int pos = tid >> 2, seg = tid & 3;
        int row = pos >> 1, side = pos & 1;
        *(uint4*)(xS + (row * 34 + side * 33) * 40 + seg * 8) = make_uint4(0u, 0u, 0u, 0u);
      }
      __syncthreads();
#pragma unroll
      for (int kidx = 0; kidx < 9; ++kidx) {
        int dy = kidx / 3, dx = kidx - dy * 3;
        bf16x8 af = *(const bf16x8*)(wS + (wave * 16 + m16) * 296 + kidx * 32 + quad * 8);
#pragma unroll
        for (int t = 0; t < 8; ++t) {
          int row = (t >> 1) + dy;
          int col = (t & 1) * 16 + m16 + dx;
          bf16x8 bf = *(const bf16x8*)(xS + (row * 34 + col) * 40 + quad * 8);
          acc[t] = __builtin_amdgcn_mfma_f32_16x16x32_bf16(af, bf, acc[t], 0, 0, 0);
        }
      }
    }

    int cob = cotile * 64 + wave * 16 + quad * 4;
#pragma unroll
    for (int i = 0; i < 4; ++i) {
      float bv = b_out[cob + i];
#pragma unroll
      for (int t = 0; t < 8; ++t) {
        int y = y0 + (t >> 1), xc = (t & 1) * 16 + m16;
        out[((size_t)(b * 512) + cob + i) * 1024 + y * 32 + xc] = acc[t][i] + bv;
      }
    }
  } else {
    short* aS = smem;            // [64][72]
    short* bS = smem + 4608;     // [128][72]
    int bid2 = blockIdx.x - 256;
    int ltile = bid2 & 7;
    int rest = bid2 >> 3;
    int ctile = rest % 12;
    int b = rest / 12;
    int l0 = ltile * 128;
    int cbase = ctile * 64;

    f32x4 acc[8];
#pragma unroll
    for (int t = 0; t < 8; ++t) acc[t] = (f32x4){0.f, 0.f, 0.f, 0.f};

    for (int ck = 0; ck < 4; ++ck) {
      __syncthreads();
#pragma unroll
      for (int r = 0; r < 4; ++r) {
        int u = r * 256 + tid;
        int c = u >> 4, s4 = u & 15;
        float4 v = *(const float4*)(wq + (size_t)(cbase + c) * 256 + ck * 64 + s4 * 4);
        unsigned int p0 = (unsigned int)f2bfbits(v.x) | ((unsigned int)f2bfbits(v.y) << 16);
        unsigned int p1 = (unsigned int)f2bfbits(v.z) | ((unsigned int)f2bfbits(v.w) << 16);
        uint2 u2; u2.x = p0; u2.y = p1;
        *(uint2*)(aS + c * 72 + s4 * 4) = u2;
      }
#pragma unroll
      for (int r = 0; r < 4; ++r) {
        int u = r * 256 + tid;
        int l = u >> 3, seg = u & 7;
        *(uint4*)(bS + l * 72 + seg * 8) =
            *(const uint4*)(xT + ((size_t)(b * 1024) + l0 + l) * 256 + ck * 64 + seg * 8);
      }
      __syncthreads();
#pragma unroll
      for (int ks = 0; ks < 2; ++ks) {
        bf16x8 af = *(const bf16x8*)(aS + (wave * 16 + m16) * 72 + ks * 32 + quad * 8);
#pragma unroll
        for (int t = 0; t < 8; ++t) {
          bf16x8 bf = *(const bf16x8*)(bS + (t * 16 + m16) * 72 + ks * 32 + quad * 8);
          acc[t] = __builtin_amdgcn_mfma_f32_16x16x32_bf16(af, bf, acc[t], 0, 0, 0);
        }
      }
    }

    __syncthreads();
    short* ldsT = smem + wave * 3072;
    int cb = cbase + wave * 16;
    bool isq = (ctile < 4);
    float bv[4];
#pragma unroll
    for (int i = 0; i < 4; ++i) bv[i] = b_qkv[cb + quad * 4 + i];
#pragma unroll
    for (int t = 0; t < 8; ++t) {
#pragma unroll
      for (int i = 0; i < 4; ++i) {
        float v = acc[t][i] + bv[i];
        if (isq) v *= 0.17677669529663689f;  // 32^-0.5, pre-rel-logits
        ldsT[(t * 16 + m16) * 24 + quad * 4 + i] = (short)f2bfbits(v);
      }
    }
    if (ctile < 8) {
      bf16* dst = isq ? qT : kR;
      int coff = isq ? cb : cb - 256;
#pragma unroll
      for (int rep = 0; rep < 4; ++rep) {
        int u = rep * 64 + lane;
        int l = u >> 1, half = u & 1;
        int c0 = coff + half * 8;
        int head = b * 8 + (c0 >> 5), d0 = c0 & 31;
        *(uint4*)(dst + ((size_t)head * 1024 + l0 + l) * 32 + d0) =
            *(const uint4*)(ldsT + l * 24 + half * 8);
      }
    } else {
      int dcol = lane >> 2, lg = lane & 3;
      int c2 = (cb - 512) + dcol;
      int head = b * 8 + (c2 >> 5), gd = c2 & 31;
#pragma unroll
      for (int s = 0; s < 4; ++s) {
        union { unsigned int w[4]; uint4 u4; } pk;
#pragma unroll
        for (int p = 0; p < 4; ++p) {
          int j0 = lg * 32 + s * 8 + p * 2;
          unsigned int u0 = (unsigned short)ldsT[j0 * 24 + dcol];
          unsigned int u1 = (unsigned short)ldsT[(j0 + 1) * 24 + dcol];
          pk.w[p] = u0 | (u1 << 16);
        }
        *(uint4*)(vW + ((size_t)head * 32 + gd) * 1024 + l0 + lg * 32 + s * 8) = pk.u4;
      }
    }
  }
}

// ---------------------------------------------------------------------------
// K3: MFMA attention. R13: double-buffered K/V staging (1 barrier/chunk);
// pS/vtS stride 68 (conflict-free writes, 4-way reads). Rel logits in f32
// (RW chunk-invariant regs, RH broadcast b128), 4 k-only QK MFMAs/chunk.
// LDS map (36864 B):
//   kS0 [64][40]sh @0 (5120) | vtS0 [32][68]sh @5120 (4352)
//   kS1 @9472 (5120)         | vtS1 @14592 (4352)          } prologue stgF
//   rhS f32 [32 j][68 r] @18944 (8704)                       aliases @0 (9072)
//   rwS f32 [64 r][36 j] @27648 (9216)  <- loop aliases as pS (4 x [16][68]sh)
// ---------------------------------------------------------------------------
__global__ __launch_bounds__(256) void attn_mfma_kernel(
    const bf16* __restrict__ qT, const bf16* __restrict__ kR, const bf16* __restrict__ vW,
    const float* __restrict__ krw, const float* __restrict__ krh,
    bf16* __restrict__ attL)
{
  __shared__ __align__(16) char smem[36864];
  short* kS0  = (short*)smem;
  short* vtS0 = (short*)(smem + 5120);
  short* kS1  = (short*)(smem + 9472);
  short* vtS1 = (short*)(smem + 14592);
  float* stgF = (float*)smem;                // prologue alias
  float* rhS  = (float*)(smem + 18944);
  float* rwS  = (float*)(smem + 27648);

  int tid = threadIdx.x;
  int lane = tid & 63, wave = tid >> 6;
  int m16 = lane & 15, quad = lane >> 4;
  int bid = blockIdx.x;
  // same head -> same blockIdx mod 8 -> same XCD (round-robin heuristic)
  int head = ((bid & 7) << 3) | ((bid >> 3) & 7);
  int qt = bid >> 6;
  int row0 = qt * 64;
  int b = head >> 3, h = head & 7;

  // staging roles + chunk-0 global prefetch (latency hidden by prologue)
  int skey = tid >> 2, sseg = tid & 3;       // K: 64 keys x 4 segs of 8
  int svd = tid >> 3, svk = tid & 7;         // V: 32 d x 8 key-segs of 8
  const bf16* kptr = kR + (size_t)head * 32768 + skey * 32 + sseg * 8;
  const bf16* vptr = vW + (size_t)head * 32768 + svd * 1024 + svk * 8;
  uint4 kreg = *(const uint4*)kptr;
  uint4 vreg = *(const uint4*)vptr;

  // per-thread prologue identity: row r, j-segment
  int r = tid >> 2, jseg = tid & 3;
  float q32[32];
  {
    const bf16* qp = qT + ((size_t)head * 1024 + row0 + r) * 32;
#pragma unroll
    for (int s4 = 0; s4 < 4; ++s4) {
      uint4 u = ((const uint4*)qp)[s4];
      q32[s4 * 8 + 0] = blo(u.x); q32[s4 * 8 + 1] = bhi(u.x);
      q32[s4 * 8 + 2] = blo(u.y); q32[s4 * 8 + 3] = bhi(u.y);
      q32[s4 * 8 + 4] = blo(u.z); q32[s4 * 8 + 5] = bhi(u.z);
      q32[s4 * 8 + 6] = blo(u.w); q32[s4 * 8 + 7] = bhi(u.w);
    }
  }

  // ---- P0: stage krw f32 (stride 36) ----
  for (int i = tid; i < 504; i += 256) {
    int row = i >> 3, d0 = (i & 7) * 4;
    *(float4*)(stgF + row * 36 + d0) = *(const float4*)(krw + row * 32 + d0);
  }
  __syncthreads();

  // ---- P1: rwS[r][j] = q[r] . krw[j - (r&31) + 31], float4 dots ----
  {
    int qi = r & 31;
#pragma unroll
    for (int jj2 = 0; jj2 < 2; ++jj2) {
      float rv[4];
#pragma unroll
      for (int jp = 0; jp < 4; ++jp) {
        int j = jseg * 8 + jj2 * 4 + jp;
        const float* kw = stgF + (j - qi + 31) * 36;
        float s1 = 0.f;
#pragma unroll
        for (int d4 = 0; d4 < 8; ++d4) {
          float4 kv = *(const float4*)(kw + d4 * 4);
          s1 += q32[d4 * 4 + 0] * kv.x + q32[d4 * 4 + 1] * kv.y +
                q32[d4 * 4 + 2] * kv.z + q32[d4 * 4 + 3] * kv.w;
        }
        rv[jp] = s1;
      }
      *(float4*)(rwS + r * 36 + jseg * 8 + jj2 * 4) = make_float4(rv[0], rv[1], rv[2], rv[3]);
    }
  }
  __syncthreads();

  // ---- P2: stage krh over stgF ----
  for (int i = tid; i < 504; i += 256) {
    int row = i >> 3, d0 = (i & 7) * 4;
    *(float4*)(stgF + row * 36 + d0) = *(const float4*)(krh + row * 32 + d0);
  }
  __syncthreads();

  // ---- P3: rhS[j][r] = q[r] . krh[j - qx + 31] (col-major for loop reads) ----
  {
    int qx = qt * 2 + (r >> 5);
#pragma unroll
    for (int jj = 0; jj < 8; ++jj) {
      int j = jseg * 8 + jj;
      const float* kh = stgF + (j - qx + 31) * 36;
      float s2 = 0.f;
#pragma unroll
      for (int d4 = 0; d4 < 8; ++d4) {
        float4 kv = *(const float4*)(kh + d4 * 4);
        s2 += q32[d4 * 4 + 0] * kv.x + q32[d4 * 4 + 1] * kv.y +
              q32[d4 * 4 + 2] * kv.z + q32[d4 * 4 + 3] * kv.w;
      }
      rhS[j * 68 + r] = s2;
    }
  }

  // ---- P4: A-frag (q, direct from global) + chunk-invariant RW registers ----
  bf16x8 afrag = *(const bf16x8*)(
      qT + ((size_t)head * 1024 + row0 + wave * 16 + m16) * 32 + quad * 8);
  float rwreg[2][4];
#pragma unroll
  for (int par = 0; par < 2; ++par)
#pragma unroll
    for (int i = 0; i < 4; ++i)
      rwreg[par][i] = rwS[(wave * 16 + quad * 4 + i) * 36 + par * 16 + m16];

  __syncthreads();   // stgF reads (P3) + rwS reads (P4) done across all waves

  // chunk-0 staging into buf0; prefetch chunk-1
  *(uint4*)(kS0 + skey * 40 + sseg * 8) = kreg;
  *(uint4*)(vtS0 + svd * 68 + svk * 8) = vreg;
  kreg = *(const uint4*)(kptr + 2048);
  vreg = *(const uint4*)(vptr + 64);

  f32x4 oacc[2];
  oacc[0] = (f32x4){0.f, 0.f, 0.f, 0.f};
  oacc[1] = (f32x4){0.f, 0.f, 0.f, 0.f};
  float rsp[4] = {0.f, 0.f, 0.f, 0.f};
  short* pS = (short*)(smem + 27648) + wave * 1088;   // [16 q][68 key-padded]

  for (int c = 0; c < 16; ++c) {
    __syncthreads();   // buf[c&1] writes visible; reads of buf[(c+1)&1] (iter c-1) done
    if (c < 15) {      // stage chunk c+1 into the other buffer (no extra barrier)
      short* kSn  = (c & 1) ? kS0 : kS1;
      short* vtSn = (c & 1) ? vtS0 : vtS1;
      *(uint4*)(kSn + skey * 40 + sseg * 8) = kreg;
      *(uint4*)(vtSn + svd * 68 + svk * 8) = vreg;
      if (c < 14) {
        kreg = *(const uint4*)(kptr + (c + 2) * 2048);
        vreg = *(const uint4*)(vptr + (c + 2) * 64);
      }
    }
    short* kS  = (c & 1) ? kS1 : kS0;
    short* vtS = (c & 1) ? vtS1 : vtS0;

    // RH for this chunk: broadcast b128 reads
    float4 rh0 = *(const float4*)(rhS + (c * 2 + 0) * 68 + wave * 16 + quad * 4);
    float4 rh1 = *(const float4*)(rhS + (c * 2 + 1) * 68 + wave * 16 + quad * 4);
    float rhv[2][4] = {{rh0.x, rh0.y, rh0.z, rh0.w}, {rh1.x, rh1.y, rh1.z, rh1.w}};

    // QK^T: 4 n-tiles, k-part only
    f32x4 sacc[4];
#pragma unroll
    for (int t = 0; t < 4; ++t) {
      bf16x8 bfK = *(const bf16x8*)(kS + (t * 16 + m16) * 40 + quad * 8);
      f32x4 z = (f32x4){0.f, 0.f, 0.f, 0.f};
      sacc[t] = __builtin_amdgcn_mfma_f32_16x16x32_bf16(afrag, bfK, z, 0, 0, 0);
    }
    // exp(s + rw + rh) (no max-sub: logits bounded), rsp partials, P -> LDS
#pragma unroll
    for (int t = 0; t < 4; ++t) {
#pragma unroll
      for (int i = 0; i < 4; ++i) {
        float e = __expf(sacc[t][i] + rwreg[t & 1][i] + rhv[t >> 1][i]);
        rsp[i] += e;
        pS[(quad * 4 + i) * 68 + t * 16 + m16] = f2bfr(e);
      }
    }
    // PV: 2 k-steps (32 keys) x 2 d-tiles; same-wave LDS roundtrip
#pragma unroll
    for (int ks2 = 0; ks2 < 2; ++ks2) {
      bf16x8 pf = *(const bf16x8*)(pS + m16 * 68 + ks2 * 32 + quad * 8);
#pragma unroll
      for (int dt = 0; dt < 2; ++dt) {
        bf16x8 vf = *(const bf16x8*)(vtS + (dt * 16 + m16) * 68 + ks2 * 32 + quad * 8);
        oacc[dt] = __builtin_amdgcn_mfma_f32_16x16x32_bf16(pf, vf, oacc[dt], 0, 0, 0);
      }
    }
  }

  // ---- epilogue: reduce row-sums within quad, normalize, store ----
#pragma unroll
  for (int off = 1; off < 16; off <<= 1)
#pragma unroll
    for (int i = 0; i < 4; ++i) rsp[i] += __shfl_xor(rsp[i], off, 64);
#pragma unroll
  for (int i = 0; i < 4; ++i) {
    float invs = 1.0f / rsp[i];
    int grow = row0 + wave * 16 + quad * 4 + i;
#pragma unroll
    for (int dt = 0; dt < 2; ++dt) {
      attL[((size_t)b * 1024 + grow) * 256 + h * 32 + dt * 16 + m16] =
          __float2bfloat16(oacc[dt][i] * invs);
    }
  }
}

// ---------------------------------------------------------------------------
// K4: attnout 1x1 conv as MFMA GEMM 256 x 1024 x 256 per batch. (R6 version)
// Runs last; overwrites the d_out ch256+ regions that hosted wo_bf.
// ---------------------------------------------------------------------------
__global__ __launch_bounds__(256) void attnout_mfma_kernel(
    const bf16* __restrict__ attL, const float* __restrict__ w, const float* __restrict__ bias,
    float* __restrict__ out)
{
  __shared__ __align__(16) short smem[13824];
  short* aS = smem;            // [64 co][72]
  short* bS = smem + 4608;     // [128 l][72]

  int tid = threadIdx.x, lane = tid & 63, wave = tid >> 6;
  int m16 = lane & 15, quad = lane >> 4;
  int l0 = blockIdx.x * 128;
  int cotile = blockIdx.y;
  int b = blockIdx.z;
  int cbase = cotile * 64;

  f32x4 acc[8];
#pragma unroll
  for (int t = 0; t < 8; ++t) acc[t] = (f32x4){0.f, 0.f, 0.f, 0.f};

  for (int ck = 0; ck < 4; ++ck) {
    __syncthreads();
#pragma unroll
    for (int r = 0; r < 4; ++r) {
      int u = r * 256 + tid;
      int c = u >> 4, s4 = u & 15;
      float4 v = *(const float4*)(w + (size_t)(cbase + c) * 256 + ck * 64 + s4 * 4);
      unsigned int p0 = (unsigned int)f2bfbits(v.x) | ((unsigned int)f2bfbits(v.y) << 16);
      unsigned int p1 = (unsigned int)f2bfbits(v.z) | ((unsigned int)f2bfbits(v.w) << 16);
      uint2 u2; u2.x = p0; u2.y = p1;
      *(uint2*)(aS + c * 72 + s4 * 4) = u2;
    }
#pragma unroll
    for (int r = 0; r < 4; ++r) {
      int u = r * 256 + tid;
      int l = u >> 3, seg = u & 7;
      *(uint4*)(bS + l * 72 + seg * 8) =
          *(const uint4*)(attL + ((size_t)(b * 1024) + l0 + l) * 256 + ck * 64 + seg * 8);
    }
    __syncthreads();
#pragma unroll
    for (int ks = 0; ks < 2; ++ks) {
      bf16x8 af = *(const bf16x8*)(aS + (wave * 16 + m16) * 72 + ks * 32 + quad * 8);
#pragma unroll
      for (int t = 0; t < 8; ++t) {
        bf16x8 bf = *(const bf16x8*)(bS + (t * 16 + m16) * 72 + ks * 32 + quad * 8);
        acc[t] = __builtin_amdgcn_mfma_f32_16x16x32_bf16(af, bf, acc[t], 0, 0, 0);
      }
    }
  }

  int co = cbase + wave * 16 + quad * 4;
#pragma unroll
  for (int i = 0; i < 4; ++i) {
    float bv = bias[co + i];
    size_t obase = ((size_t)(b * 512) + 256 + co + i) * 1024 + l0;
#pragma unroll
    for (int t = 0; t < 8; ++t)
      out[obase + t * 16 + m16] = acc[t][i] + bv;
  }
}

// ---------------------------------------------------------------------------
extern "C" void kernel_launch(void* const* d_in, const int* in_sizes, int n_in,
                              void* d_out, int out_size, void* d_ws, size_t ws_size,
                              hipStream_t stream) {
  const float* x      = (const float*)d_in[0];
  const float* w_qkv  = (const float*)d_in[1];
  const float* b_qkv  = (const float*)d_in[2];
  const float* w_attn = (const float*)d_in[3];
  const float* b_attn = (const float*)d_in[4];
  const float* w_out  = (const float*)d_in[5];
  const float* b_out  = (const float*)d_in[6];
  const float* krw    = (const float*)d_in[7];
  const float* krh    = (const float*)d_in[8];
  float* out = (float*)d_out;

  bf16* ws    = (bf16*)d_ws;
  bf16* xT    = ws;                 // [0, 2,097,152)  read by fused conv3+qkv
  bf16* attL  = ws;                 // alias of xT     (attn -> attnout, after fused)
  bf16* qT    = ws + 2097152;       // [2,097,152, 4,194,304)
  bf16* kR    = ws + 4194304;       // [4,194,304, 6,291,456)
  bf16* vW    = ws + 6291456;       // [6,291,456, 8,388,608)  exact 16 MB fit

  // wo_bf in d_out's attention half (dead until attnout overwrites it)
  bf16* wob0 = (bf16*)(out + (size_t)(0 * 512 + 256) * 1024);
  bf16* wob1 = (bf16*)(out + (size_t)(1 * 512 + 256) * 1024);

  prep_kernel<<<dim3(2084), 256, 0, stream>>>(x, w_out, xT, wob0, wob1);
  convqkv_kernel<<<dim3(1024), 256, 0, stream>>>(xT, wob0, wob1, b_out, out,
                                                 w_qkv, b_qkv, qT, kR, vW);
  attn_mfma_kernel<<<dim3(1024), 256, 0, stream>>>(qT, kR, vW, krw, krh, attL);
  attnout_mfma_kernel<<<dim3(8, 4, 8), 256, 0, stream>>>(attL, w_attn, b_attn, out);
}